// Round 1
// baseline (4040.191 us; speedup 1.0000x reference)
//
#include <hip/hip_runtime.h>

#define NB 16
#define NC 4
#define WD 17
#define NPIX 289
#define PWD 19
#define PPIX 361   // 19*19 zero-padded cell planes
#define FWD 21
#define FPIX 441   // 21*21 zero-padded food plane
#define NT 320     // 5 waves; threads 0..288 map to pixels

__global__ __launch_bounds__(NT, 1) void ca_kernel(
    const float* __restrict__ cell_in, const float* __restrict__ food_in,
    const int* __restrict__ steps_in,
    const float* __restrict__ fc1_w, const float* __restrict__ fc1_b,
    const float* __restrict__ fc2_w, const float* __restrict__ fc2_b,
    float* __restrict__ out)
{
  __shared__ float s_cell[NC][PPIX];
  __shared__ float s_x0[PPIX];
  __shared__ float4 s_v4[73];          // 292 floats, [289..291] = -1 sentinel
  __shared__ float s_food[FPIX];
  __shared__ float s_w1[64][16];       // fc1 rows padded to 16 for b128 loads
  __shared__ float s_w2t[64][4];       // fc2 transposed: [o][d]
  __shared__ float s_b1[64];
  __shared__ float s_b2[4];
  __shared__ int   s_red[8];
  __shared__ float s_sum[8];
  float* s_v = (float*)s_v4;

  const int b    = blockIdx.x;
  const int tid  = threadIdx.x;
  const int lane = tid & 63;
  const int wv   = tid >> 6;
  const bool act = (tid < NPIX);
  const int p  = tid;
  const int py = p / WD;
  const int px = p - py * WD;
  const int pp = (py + 1) * PWD + (px + 1);   // only dereferenced under act
  const int fp = (py + 2) * FWD + (px + 2);

  // ---- init LDS (zero borders, sentinel pads) ----
  for (int i = tid; i < NC * PPIX; i += NT) (&s_cell[0][0])[i] = 0.f;
  for (int i = tid; i < PPIX; i += NT) s_x0[i] = 0.f;
  for (int i = tid; i < FPIX; i += NT) s_food[i] = 0.f;
  for (int i = tid; i < 292; i += NT) s_v[i] = -1.f;
  for (int i = tid; i < 64 * 16; i += NT) (&s_w1[0][0])[i] = 0.f;
  __syncthreads();

  float c3_init = 0.f;
  if (act) {
    const float* cb = cell_in + (size_t)b * (NC * NPIX);
    s_cell[0][pp] = cb[p];
    s_cell[1][pp] = cb[NPIX + p];
    s_cell[2][pp] = cb[2 * NPIX + p];
    c3_init = cb[3 * NPIX + p];
    s_food[fp] = food_in[(size_t)b * NPIX + p];
  }
  for (int i = tid; i < 768; i += NT) s_w1[i / 12][i % 12] = fc1_w[i];
  for (int i = tid; i < 256; i += NT) s_w2t[i & 63][i >> 6] = fc2_w[i];
  if (tid < 64) s_b1[tid] = fc1_b[tid];
  if (tid < 4)  s_b2[tid] = fc2_b[tid];
  __syncthreads();

  // ---- scent = conv5x5(food), constant over steps; becomes cell ch3 ----
  float scent = 0.f;
  if (act) {
    const float w5[5][5] = {
      {0.f,0.125f,0.25f,0.125f,0.f},
      {0.125f,0.25f,0.5f,0.25f,0.125f},
      {0.25f,0.5f,1.0f,0.5f,0.25f},
      {0.125f,0.25f,0.5f,0.25f,0.125f},
      {0.f,0.125f,0.25f,0.125f,0.f}};
    #pragma unroll
    for (int ky = 0; ky < 5; ++ky) {
      #pragma unroll
      for (int kx = 0; kx < 5; ++kx) {
        if (w5[ky][kx] != 0.f)
          scent = fmaf(w5[ky][kx], s_food[fp + (ky - 2) * FWD + (kx - 2)], scent);
      }
    }
    s_cell[3][pp] = scent;   // ch3 plane is constant = scent forever
  }
  __syncthreads();

  // ---- constant Sobel derivs of scent + initial living count ----
  float dxs = 0.f, dys = 0.f;
  {
    bool alive = false;
    if (act) {
      float t00 = s_cell[3][pp-PWD-1], t01 = s_cell[3][pp-PWD], t02 = s_cell[3][pp-PWD+1];
      float t10 = s_cell[3][pp-1],                              t12 = s_cell[3][pp+1];
      float t20 = s_cell[3][pp+PWD-1], t21 = s_cell[3][pp+PWD], t22 = s_cell[3][pp+PWD+1];
      dxs = ((t02 - t00) + 2.f * (t12 - t10) + (t22 - t20)) * 0.125f;
      dys = ((t20 - t00) + 2.f * (t21 - t01) + (t22 - t02)) * 0.125f;
      alive = s_cell[0][pp] > 0.1f;
    }
    unsigned long long bm = __ballot(alive ? 1 : 0);
    if (lane == 0) s_red[wv] = (int)__popcll(bm);
  }
  __syncthreads();
  int k_cnt = s_red[0] + s_red[1] + s_red[2] + s_red[3] + s_red[4];

  int steps = steps_in[0];
  if (steps < 0 || steps > 1000000) steps = (int)__int_as_float(steps); // fp32-scalar fallback

  float o0 = 0.f, o1 = 0.f, o2 = 0.f, o3 = c3_init;
  if (act) { o0 = s_cell[0][pp]; o1 = s_cell[1][pp]; o2 = s_cell[2][pp]; }

  for (int s = 0; s < steps; ++s) {
    float x0 = 0.f, x1 = 0.f, x2 = 0.f, x3 = 0.f;
    bool pre = false;
    if (act) {
      const int q = pp;
      float a00=s_cell[0][q-PWD-1], a01=s_cell[0][q-PWD], a02=s_cell[0][q-PWD+1];
      float a10=s_cell[0][q-1],     a11=s_cell[0][q],     a12=s_cell[0][q+1];
      float a20=s_cell[0][q+PWD-1], a21=s_cell[0][q+PWD], a22=s_cell[0][q+PWD+1];
      float b00=s_cell[1][q-PWD-1], b01=s_cell[1][q-PWD], b02=s_cell[1][q-PWD+1];
      float b10=s_cell[1][q-1],     b11=s_cell[1][q],     b12=s_cell[1][q+1];
      float b20=s_cell[1][q+PWD-1], b21=s_cell[1][q+PWD], b22=s_cell[1][q+PWD+1];
      float c00=s_cell[2][q-PWD-1], c01=s_cell[2][q-PWD], c02=s_cell[2][q-PWD+1];
      float c10=s_cell[2][q-1],     c11=s_cell[2][q],     c12=s_cell[2][q+1];
      float c20=s_cell[2][q+PWD-1], c21=s_cell[2][q+PWD], c22=s_cell[2][q+PWD+1];

      float mx = fmaxf(fmaxf(fmaxf(fmaxf(a00,a01),fmaxf(a02,a10)),
                             fmaxf(fmaxf(a11,a12),fmaxf(a20,a21))), a22);
      pre = mx > 0.1f;

      float y0=a11, y1=b11, y2=c11, y3=scent;
      float y4=((a02-a00)+2.f*(a12-a10)+(a22-a20))*0.125f;
      float y5=((b02-b00)+2.f*(b12-b10)+(b22-b20))*0.125f;
      float y6=((c02-c00)+2.f*(c12-c10)+(c22-c20))*0.125f;
      float y7=dxs;
      float y8=((a20-a00)+2.f*(a21-a01)+(a22-a02))*0.125f;
      float y9=((b20-b00)+2.f*(b21-b01)+(b22-b02))*0.125f;
      float y10=((c20-c00)+2.f*(c21-c01)+(c22-c02))*0.125f;
      float y11=dys;

      float acc0=0.f, acc1=0.f, acc2=0.f, acc3=0.f;
      #pragma unroll 16
      for (int o = 0; o < 64; ++o) {
        float t;
        t = s_w1[o][0] * y0;
        t = fmaf(s_w1[o][1],  y1,  t);
        t = fmaf(s_w1[o][2],  y2,  t);
        t = fmaf(s_w1[o][3],  y3,  t);
        t = fmaf(s_w1[o][4],  y4,  t);
        t = fmaf(s_w1[o][5],  y5,  t);
        t = fmaf(s_w1[o][6],  y6,  t);
        t = fmaf(s_w1[o][7],  y7,  t);
        t = fmaf(s_w1[o][8],  y8,  t);
        t = fmaf(s_w1[o][9],  y9,  t);
        t = fmaf(s_w1[o][10], y10, t);
        t = fmaf(s_w1[o][11], y11, t);
        t += s_b1[o];
        t = fmaxf(t, 0.f);
        acc0 = fmaf(s_w2t[o][0], t, acc0);
        acc1 = fmaf(s_w2t[o][1], t, acc1);
        acc2 = fmaf(s_w2t[o][2], t, acc2);
        acc3 = fmaf(s_w2t[o][3], t, acc3);
      }
      x0 = a11   + (acc0 + s_b2[0]);
      x1 = b11   + (acc1 + s_b2[1]);
      x2 = c11   + (acc2 + s_b2[2]);
      x3 = scent + (acc3 + s_b2[3]);
      s_x0[pp] = x0;
    }
    __syncthreads();
    if (act) {
      const int q = pp;
      float m0 = fmaxf(fmaxf(fmaxf(fmaxf(s_x0[q-PWD-1],s_x0[q-PWD]),
                                   fmaxf(s_x0[q-PWD+1],s_x0[q-1])),
                             fmaxf(fmaxf(s_x0[q],s_x0[q+1]),
                                   fmaxf(s_x0[q+PWD-1],s_x0[q+PWD]))), s_x0[q+PWD+1]);
      bool km = pre && (m0 > 0.1f);
      o0 = km ? fminf(fmaxf(x0,   0.f),  1.f) : 0.f;   // clip[-10,10] then [0,1] == [0,1]
      o1 = km ? fminf(fmaxf(x1, -10.f), 10.f) : 0.f;
      o2 = km ? fminf(fmaxf(x2, -10.f), 10.f) : 0.f;
      o3 = km ? fminf(fmaxf(x3, -10.f), 10.f) : 0.f;
      s_v[p] = o0;
    }
    __syncthreads();
    {
      int k_idx = k_cnt - 1;
      if (k_idx < 0) k_idx += NPIX;   // torch negative-index wrap
      bool alive = false;
      if (act) {
        const float vi = o0;
        int cnt = 0;
        #pragma unroll 8
        for (int j = 0; j < 73; ++j) {    // broadcast reads: uniform addr across lanes
          float4 v4 = s_v4[j];
          cnt += (v4.x > vi);
          cnt += (v4.y > vi);
          cnt += (v4.z > vi);
          cnt += (v4.w > vi);
        }
        // keep v iff strict-rank <= k_idx  <=>  v >= kth-largest (ties included)
        if (cnt > k_idx) o0 = 0.f;
        s_cell[0][pp] = o0;
        s_cell[1][pp] = o1;
        s_cell[2][pp] = o2;
        alive = o0 > 0.1f;
      }
      unsigned long long bm = __ballot(alive ? 1 : 0);
      if (lane == 0) s_red[wv] = (int)__popcll(bm);
    }
    __syncthreads();
    k_cnt = s_red[0] + s_red[1] + s_red[2] + s_red[3] + s_red[4];
  }

  // ---- outputs: cell | food | total_pixel_val | living_count ----
  if (act) {
    float* oc = out + (size_t)b * (NC * NPIX);
    oc[p]            = o0;
    oc[NPIX + p]     = o1;
    oc[2 * NPIX + p] = o2;
    oc[3 * NPIX + p] = o3;
    out[NB * NC * NPIX + (size_t)b * NPIX + p] = food_in[(size_t)b * NPIX + p];
  }
  float sv = act ? o0 : 0.f;
  #pragma unroll
  for (int off = 32; off > 0; off >>= 1) sv += __shfl_down(sv, off, 64);
  if (lane == 0) s_sum[wv] = sv;
  __syncthreads();
  if (tid == 0) {
    out[NB * NC * NPIX + NB * NPIX + b]      = s_sum[0] + s_sum[1] + s_sum[2] + s_sum[3] + s_sum[4];
    out[NB * NC * NPIX + NB * NPIX + NB + b] = (float)k_cnt;
  }
}

extern "C" void kernel_launch(void* const* d_in, const int* in_sizes, int n_in,
                              void* d_out, int out_size, void* d_ws, size_t ws_size,
                              hipStream_t stream) {
  (void)in_sizes; (void)n_in; (void)d_ws; (void)ws_size; (void)out_size;
  ca_kernel<<<dim3(NB), dim3(NT), 0, stream>>>(
      (const float*)d_in[0], (const float*)d_in[1], (const int*)d_in[2],
      (const float*)d_in[3], (const float*)d_in[4], (const float*)d_in[5],
      (const float*)d_in[6], (float*)d_out);
}

// Round 2
// 3775.746 us; speedup vs baseline: 1.0700x; 1.0700x over previous
//
#include <hip/hip_runtime.h>

#define NB 16
#define WD 17
#define NPIX 289
#define PWD 19
#define PPIX 361   // 19*19 zero-padded planes
#define FWD 21
#define FPIX 441   // 21*21 zero-padded food
#define NT 512     // 8 waves: waves 0..3 pixel-parallel ("act"), all 8 hidden-parallel

__device__ __forceinline__ float rl(float x, int l) {
  return __int_as_float(__builtin_amdgcn_readlane(__float_as_int(x), l));
}

__global__ __launch_bounds__(NT, 2) void ca_kernel(
    const float* __restrict__ cell_in, const float* __restrict__ food_in,
    const int* __restrict__ steps_in,
    const float* __restrict__ fc1_w, const float* __restrict__ fc1_b,
    const float* __restrict__ fc2_w, const float* __restrict__ fc2_b,
    float* __restrict__ out)
{
  __shared__ float  s_cell[3][PPIX];   // ch0..2 (ch3 == scent, kept in regs)
  __shared__ float  s_x0[PPIX];        // pre-mask x0 plane (borders stay 0)
  __shared__ float4 s_v4[128];         // 512 floats; [289..511] = -1 sentinels
  __shared__ float4 s_y4[3][292];      // per-pixel y (12 vals as 3 float4)
  __shared__ float4 s_pd[8][292];      // per-wave partial deltas
  __shared__ int    s_red[8];
  __shared__ float  s_sum[8];
  float* s_v    = (float*)s_v4;
  float* s_food = (float*)&s_pd[0][0];   // init-only alias (441 floats)
  float* s_wst  = (float*)&s_pd[4][0];   // init-only alias (1088 floats)

  const int  b    = blockIdx.x;
  const int  tid  = threadIdx.x;
  const int  lane = tid & 63;
  const int  wv   = tid >> 6;
  const bool act  = tid < 256;
  const bool has2 = tid < 33;
  const int  p1   = tid;         // pixel 1 (valid if act)
  const int  p2   = tid + 256;   // pixel 2 (valid if has2)
  const int  py1 = p1 / WD, px1 = p1 - py1 * WD;
  const int  py2 = p2 / WD, px2 = p2 - py2 * WD;
  const int  pp1 = (py1 + 1) * PWD + px1 + 1;
  const int  pp2 = (py2 + 1) * PWD + px2 + 1;
  const int  fp1 = (py1 + 2) * FWD + px1 + 2;
  const int  fp2 = (py2 + 2) * FWD + px2 + 2;

  // ---------------- init ----------------
  for (int i = tid; i < 3 * PPIX; i += NT) (&s_cell[0][0])[i] = 0.f;
  for (int i = tid; i < PPIX; i += NT) s_x0[i] = 0.f;
  for (int i = tid; i < 512; i += NT) s_v[i] = -1.f;
  for (int i = tid; i < FPIX; i += NT) s_food[i] = 0.f;
  for (int i = tid; i < 768; i += NT) s_wst[i] = fc1_w[i];
  for (int i = tid; i < 64; i += NT) s_wst[768 + i] = fc1_b[i];
  for (int i = tid; i < 256; i += NT) s_wst[832 + i] = fc2_w[i];
  __syncthreads();

  float cur0a = 0.f, cur1a = 0.f, cur2a = 0.f, o3a = 0.f;
  float cur0b = 0.f, cur1b = 0.f, cur2b = 0.f, o3b = 0.f;
  if (act) {
    const float* cb = cell_in + (size_t)b * (4 * NPIX);
    cur0a = cb[p1]; cur1a = cb[NPIX + p1]; cur2a = cb[2 * NPIX + p1];
    o3a = cb[3 * NPIX + p1];
    s_cell[0][pp1] = cur0a; s_cell[1][pp1] = cur1a; s_cell[2][pp1] = cur2a;
    s_food[fp1] = food_in[(size_t)b * NPIX + p1];
  }
  if (has2) {
    const float* cb = cell_in + (size_t)b * (4 * NPIX);
    cur0b = cb[p2]; cur1b = cb[NPIX + p2]; cur2b = cb[2 * NPIX + p2];
    o3b = cb[3 * NPIX + p2];
    s_cell[0][pp2] = cur0b; s_cell[1][pp2] = cur1b; s_cell[2][pp2] = cur2b;
    s_food[fp2] = food_in[(size_t)b * NPIX + p2];
  }
  __syncthreads();

  // weights -> VGPRs (ds_read results stay in vector regs)
  const int h0 = wv * 8;
  float w1r[8][12], b1r[8], w2r[8][4];
  #pragma unroll
  for (int o = 0; o < 8; ++o) {
    #pragma unroll
    for (int d = 0; d < 12; ++d) w1r[o][d] = s_wst[(h0 + o) * 12 + d];
    b1r[o] = s_wst[768 + h0 + o];
    #pragma unroll
    for (int c = 0; c < 4; ++c) w2r[o][c] = s_wst[832 + c * 64 + h0 + o];
  }
  const float b2r0 = fc2_b[0], b2r1 = fc2_b[1], b2r2 = fc2_b[2], b2r3 = fc2_b[3];

  // scent (constant over steps) via s_x0 as temp plane
  float scent_a = 0.f, scent_b = 0.f;
  {
    const float w5[5][5] = {
      {0.f,0.125f,0.25f,0.125f,0.f},
      {0.125f,0.25f,0.5f,0.25f,0.125f},
      {0.25f,0.5f,1.0f,0.5f,0.25f},
      {0.125f,0.25f,0.5f,0.25f,0.125f},
      {0.f,0.125f,0.25f,0.125f,0.f}};
    if (act) {
      float s = 0.f;
      #pragma unroll
      for (int ky = 0; ky < 5; ++ky)
        #pragma unroll
        for (int kx = 0; kx < 5; ++kx)
          if (w5[ky][kx] != 0.f) s = fmaf(w5[ky][kx], s_food[fp1 + (ky-2)*FWD + kx-2], s);
      scent_a = s;
    }
    if (has2) {
      float s = 0.f;
      #pragma unroll
      for (int ky = 0; ky < 5; ++ky)
        #pragma unroll
        for (int kx = 0; kx < 5; ++kx)
          if (w5[ky][kx] != 0.f) s = fmaf(w5[ky][kx], s_food[fp2 + (ky-2)*FWD + kx-2], s);
      scent_b = s;
    }
  }
  __syncthreads();             // done with s_food alias
  if (act)  s_x0[pp1] = scent_a;
  if (has2) s_x0[pp2] = scent_b;
  __syncthreads();

  float dxsa = 0.f, dysa = 0.f, dxsb = 0.f, dysb = 0.f;
  if (act) {
    int q = pp1;
    float t00=s_x0[q-PWD-1], t01=s_x0[q-PWD], t02=s_x0[q-PWD+1];
    float t10=s_x0[q-1],                      t12=s_x0[q+1];
    float t20=s_x0[q+PWD-1], t21=s_x0[q+PWD], t22=s_x0[q+PWD+1];
    dxsa = ((t02-t00)+2.f*(t12-t10)+(t22-t20))*0.125f;
    dysa = ((t20-t00)+2.f*(t21-t01)+(t22-t02))*0.125f;
  }
  if (has2) {
    int q = pp2;
    float t00=s_x0[q-PWD-1], t01=s_x0[q-PWD], t02=s_x0[q-PWD+1];
    float t10=s_x0[q-1],                      t12=s_x0[q+1];
    float t20=s_x0[q+PWD-1], t21=s_x0[q+PWD], t22=s_x0[q+PWD+1];
    dxsb = ((t02-t00)+2.f*(t12-t10)+(t22-t20))*0.125f;
    dysb = ((t20-t00)+2.f*(t21-t01)+(t22-t02))*0.125f;
  }
  {
    bool a1 = act && (cur0a > 0.1f);
    bool a2 = has2 && (cur0b > 0.1f);
    unsigned long long m1 = __ballot(a1), m2 = __ballot(a2);
    if (lane == 0) s_red[wv] = (int)__popcll(m1) + (int)__popcll(m2);
  }
  __syncthreads();
  int k_cnt = s_red[0] + s_red[1] + s_red[2] + s_red[3];

  const int steps = steps_in[0];
  float o0a = cur0a, o1a = cur1a, o2a = cur2a;
  float o0b = cur0b, o1b = cur1b, o2b = cur2b;
  float x1a=0.f,x2a=0.f,x3a=0.f,x1b=0.f,x2b=0.f,x3b=0.f,x0a=0.f,x0b=0.f;
  bool prea = false, preb = false;

  for (int s = 0; s < steps; ++s) {
    // ---- A: stencils -> y (pixel-parallel) ----
    if (act) {
      int q = pp1;
      float a00=s_cell[0][q-PWD-1], a01=s_cell[0][q-PWD], a02=s_cell[0][q-PWD+1];
      float a10=s_cell[0][q-1],     a12=s_cell[0][q+1];
      float a20=s_cell[0][q+PWD-1], a21=s_cell[0][q+PWD], a22=s_cell[0][q+PWD+1];
      float b00=s_cell[1][q-PWD-1], b01=s_cell[1][q-PWD], b02=s_cell[1][q-PWD+1];
      float b10=s_cell[1][q-1],     b12=s_cell[1][q+1];
      float b20=s_cell[1][q+PWD-1], b21=s_cell[1][q+PWD], b22=s_cell[1][q+PWD+1];
      float c00=s_cell[2][q-PWD-1], c01=s_cell[2][q-PWD], c02=s_cell[2][q-PWD+1];
      float c10=s_cell[2][q-1],     c12=s_cell[2][q+1];
      float c20=s_cell[2][q+PWD-1], c21=s_cell[2][q+PWD], c22=s_cell[2][q+PWD+1];
      float mx = fmaxf(fmaxf(fmaxf(fmaxf(a00,a01),fmaxf(a02,a10)),
                             fmaxf(fmaxf(o0a,a12),fmaxf(a20,a21))), a22);
      prea = mx > 0.1f;
      float4 q0, q1, q2;
      q0.x=o0a; q0.y=o1a; q0.z=o2a; q0.w=scent_a;
      q1.x=((a02-a00)+2.f*(a12-a10)+(a22-a20))*0.125f;
      q1.y=((b02-b00)+2.f*(b12-b10)+(b22-b20))*0.125f;
      q1.z=((c02-c00)+2.f*(c12-c10)+(c22-c20))*0.125f;
      q1.w=dxsa;
      q2.x=((a20-a00)+2.f*(a21-a01)+(a22-a02))*0.125f;
      q2.y=((b20-b00)+2.f*(b21-b01)+(b22-b02))*0.125f;
      q2.z=((c20-c00)+2.f*(c21-c01)+(c22-c02))*0.125f;
      q2.w=dysa;
      s_y4[0][p1]=q0; s_y4[1][p1]=q1; s_y4[2][p1]=q2;
    }
    if (has2) {
      int q = pp2;
      float a00=s_cell[0][q-PWD-1], a01=s_cell[0][q-PWD], a02=s_cell[0][q-PWD+1];
      float a10=s_cell[0][q-1],     a12=s_cell[0][q+1];
      float a20=s_cell[0][q+PWD-1], a21=s_cell[0][q+PWD], a22=s_cell[0][q+PWD+1];
      float b00=s_cell[1][q-PWD-1], b01=s_cell[1][q-PWD], b02=s_cell[1][q-PWD+1];
      float b10=s_cell[1][q-1],     b12=s_cell[1][q+1];
      float b20=s_cell[1][q+PWD-1], b21=s_cell[1][q+PWD], b22=s_cell[1][q+PWD+1];
      float c00=s_cell[2][q-PWD-1], c01=s_cell[2][q-PWD], c02=s_cell[2][q-PWD+1];
      float c10=s_cell[2][q-1],     c12=s_cell[2][q+1];
      float c20=s_cell[2][q+PWD-1], c21=s_cell[2][q+PWD], c22=s_cell[2][q+PWD+1];
      float mx = fmaxf(fmaxf(fmaxf(fmaxf(a00,a01),fmaxf(a02,a10)),
                             fmaxf(fmaxf(o0b,a12),fmaxf(a20,a21))), a22);
      preb = mx > 0.1f;
      float4 q0, q1, q2;
      q0.x=o0b; q0.y=o1b; q0.z=o2b; q0.w=scent_b;
      q1.x=((a02-a00)+2.f*(a12-a10)+(a22-a20))*0.125f;
      q1.y=((b02-b00)+2.f*(b12-b10)+(b22-b20))*0.125f;
      q1.z=((c02-c00)+2.f*(c12-c10)+(c22-c20))*0.125f;
      q1.w=dxsb;
      q2.x=((a20-a00)+2.f*(a21-a01)+(a22-a02))*0.125f;
      q2.y=((b20-b00)+2.f*(b21-b01)+(b22-b02))*0.125f;
      q2.z=((c20-c00)+2.f*(c21-c01)+(c22-c02))*0.125f;
      q2.w=dysb;
      s_y4[0][p2]=q0; s_y4[1][p2]=q1; s_y4[2][p2]=q2;
    }
    __syncthreads();

    // ---- B: hidden-parallel MLP, weights in VGPRs ----
    #pragma unroll 1
    for (int c = 0; c < 5; ++c) {
      int p = c * 64 + lane;
      int pc = p < NPIX ? p : NPIX - 1;
      float4 q0 = s_y4[0][pc], q1 = s_y4[1][pc], q2 = s_y4[2][pc];
      float4 acc; acc.x = 0.f; acc.y = 0.f; acc.z = 0.f; acc.w = 0.f;
      #pragma unroll
      for (int o = 0; o < 8; ++o) {
        float g = b1r[o];
        g = fmaf(w1r[o][0],  q0.x, g);
        g = fmaf(w1r[o][1],  q0.y, g);
        g = fmaf(w1r[o][2],  q0.z, g);
        g = fmaf(w1r[o][3],  q0.w, g);
        g = fmaf(w1r[o][4],  q1.x, g);
        g = fmaf(w1r[o][5],  q1.y, g);
        g = fmaf(w1r[o][6],  q1.z, g);
        g = fmaf(w1r[o][7],  q1.w, g);
        g = fmaf(w1r[o][8],  q2.x, g);
        g = fmaf(w1r[o][9],  q2.y, g);
        g = fmaf(w1r[o][10], q2.z, g);
        g = fmaf(w1r[o][11], q2.w, g);
        g = fmaxf(g, 0.f);
        acc.x = fmaf(w2r[o][0], g, acc.x);
        acc.y = fmaf(w2r[o][1], g, acc.y);
        acc.z = fmaf(w2r[o][2], g, acc.z);
        acc.w = fmaf(w2r[o][3], g, acc.w);
      }
      if (p < NPIX) s_pd[wv][p] = acc;
    }
    __syncthreads();

    // ---- C: combine partials -> x; stage x0 plane ----
    if (act) {
      float4 d = s_pd[0][p1];
      #pragma unroll
      for (int w = 1; w < 8; ++w) {
        float4 t = s_pd[w][p1];
        d.x += t.x; d.y += t.y; d.z += t.z; d.w += t.w;
      }
      x0a = o0a + d.x + b2r0; x1a = o1a + d.y + b2r1;
      x2a = o2a + d.z + b2r2; x3a = scent_a + d.w + b2r3;
      s_x0[pp1] = x0a;
    }
    if (has2) {
      float4 d = s_pd[0][p2];
      #pragma unroll
      for (int w = 1; w < 8; ++w) {
        float4 t = s_pd[w][p2];
        d.x += t.x; d.y += t.y; d.z += t.z; d.w += t.w;
      }
      x0b = o0b + d.x + b2r0; x1b = o1b + d.y + b2r1;
      x2b = o2b + d.z + b2r2; x3b = scent_b + d.w + b2r3;
      s_x0[pp2] = x0b;
    }
    __syncthreads();

    // ---- D: post-mask maxpool, clip, stage rank values ----
    if (act) {
      int q = pp1;
      float m0 = fmaxf(fmaxf(fmaxf(fmaxf(s_x0[q-PWD-1],s_x0[q-PWD]),
                                   fmaxf(s_x0[q-PWD+1],s_x0[q-1])),
                             fmaxf(fmaxf(x0a,s_x0[q+1]),
                                   fmaxf(s_x0[q+PWD-1],s_x0[q+PWD]))), s_x0[q+PWD+1]);
      bool km = prea && (m0 > 0.1f);
      o0a = km ? fminf(fmaxf(x0a,   0.f),  1.f) : 0.f;
      o1a = km ? fminf(fmaxf(x1a, -10.f), 10.f) : 0.f;
      o2a = km ? fminf(fmaxf(x2a, -10.f), 10.f) : 0.f;
      o3a = km ? fminf(fmaxf(x3a, -10.f), 10.f) : 0.f;
      s_v[p1] = o0a; s_cell[1][pp1] = o1a; s_cell[2][pp1] = o2a;
    }
    if (has2) {
      int q = pp2;
      float m0 = fmaxf(fmaxf(fmaxf(fmaxf(s_x0[q-PWD-1],s_x0[q-PWD]),
                                   fmaxf(s_x0[q-PWD+1],s_x0[q-1])),
                             fmaxf(fmaxf(x0b,s_x0[q+1]),
                                   fmaxf(s_x0[q+PWD-1],s_x0[q+PWD]))), s_x0[q+PWD+1]);
      bool km = preb && (m0 > 0.1f);
      o0b = km ? fminf(fmaxf(x0b,   0.f),  1.f) : 0.f;
      o1b = km ? fminf(fmaxf(x1b, -10.f), 10.f) : 0.f;
      o2b = km ? fminf(fmaxf(x2b, -10.f), 10.f) : 0.f;
      o3b = km ? fminf(fmaxf(x3b, -10.f), 10.f) : 0.f;
      s_v[p2] = o0b; s_cell[1][pp2] = o1b; s_cell[2][pp2] = o2b;
    }
    __syncthreads();

    // ---- E: k-th-largest keep via strict-rank (readlane broadcast) ----
    {
      int k_idx = k_cnt - 1;
      if (k_idx < 0) k_idx += NPIX;
      bool aliveA = false, aliveB = false;
      if (act) {
        if (k_idx < NPIX - 1) {
          float4 r0 = s_v4[lane];
          float4 r1 = s_v4[64 + lane];
          const float vi1 = o0a;
          const float vi2 = has2 ? o0b : 3.0e38f;
          int c1 = 0, c2 = 0;
          #pragma unroll
          for (int j = 0; j < 64; ++j) {
            float v0 = rl(r0.x, j), v1 = rl(r0.y, j), v2 = rl(r0.z, j), v3 = rl(r0.w, j);
            c1 += (v0 > vi1); c2 += (v0 > vi2);
            c1 += (v1 > vi1); c2 += (v1 > vi2);
            c1 += (v2 > vi1); c2 += (v2 > vi2);
            c1 += (v3 > vi1); c2 += (v3 > vi2);
          }
          #pragma unroll
          for (int j = 0; j < 9; ++j) {
            float v0 = rl(r1.x, j), v1 = rl(r1.y, j), v2 = rl(r1.z, j), v3 = rl(r1.w, j);
            c1 += (v0 > vi1); c2 += (v0 > vi2);
            c1 += (v1 > vi1); c2 += (v1 > vi2);
            c1 += (v2 > vi1); c2 += (v2 > vi2);
            c1 += (v3 > vi1); c2 += (v3 > vi2);
          }
          if (c1 > k_idx) o0a = 0.f;
          if (has2 && c2 > k_idx) o0b = 0.f;
        }
        s_cell[0][pp1] = o0a;
        if (has2) s_cell[0][pp2] = o0b;
        aliveA = o0a > 0.1f;
        aliveB = has2 && (o0b > 0.1f);
      }
      unsigned long long mA = __ballot(aliveA), mB = __ballot(aliveB);
      if (lane == 0) s_red[wv] = (int)__popcll(mA) + (int)__popcll(mB);
    }
    __syncthreads();
    k_cnt = s_red[0] + s_red[1] + s_red[2] + s_red[3];
  }

  // ---- outputs: cell | food | total_pixel_val | living_count ----
  if (act) {
    float* oc = out + (size_t)b * (4 * NPIX);
    oc[p1] = o0a; oc[NPIX + p1] = o1a; oc[2*NPIX + p1] = o2a; oc[3*NPIX + p1] = o3a;
    out[NB*4*NPIX + (size_t)b * NPIX + p1] = food_in[(size_t)b * NPIX + p1];
  }
  if (has2) {
    float* oc = out + (size_t)b * (4 * NPIX);
    oc[p2] = o0b; oc[NPIX + p2] = o1b; oc[2*NPIX + p2] = o2b; oc[3*NPIX + p2] = o3b;
    out[NB*4*NPIX + (size_t)b * NPIX + p2] = food_in[(size_t)b * NPIX + p2];
  }
  float sv = o0a + (has2 ? o0b : 0.f);
  #pragma unroll
  for (int off = 32; off > 0; off >>= 1) sv += __shfl_down(sv, off, 64);
  if (lane == 0) s_sum[wv] = sv;
  __syncthreads();
  if (tid == 0) {
    float tot = 0.f;
    #pragma unroll
    for (int w = 0; w < 8; ++w) tot += s_sum[w];
    out[NB*4*NPIX + NB*NPIX + b]      = tot;
    out[NB*4*NPIX + NB*NPIX + NB + b] = (float)k_cnt;
  }
}

extern "C" void kernel_launch(void* const* d_in, const int* in_sizes, int n_in,
                              void* d_out, int out_size, void* d_ws, size_t ws_size,
                              hipStream_t stream) {
  (void)in_sizes; (void)n_in; (void)d_ws; (void)ws_size; (void)out_size;
  ca_kernel<<<dim3(NB), dim3(NT), 0, stream>>>(
      (const float*)d_in[0], (const float*)d_in[1], (const int*)d_in[2],
      (const float*)d_in[3], (const float*)d_in[4], (const float*)d_in[5],
      (const float*)d_in[6], (float*)d_out);
}

// Round 3
// 3094.701 us; speedup vs baseline: 1.3055x; 1.2201x over previous
//
#include <hip/hip_runtime.h>

#define NB 16
#define WD 17
#define NPIX 289
#define PWD 19
#define PPIX 361   // 19*19 zero-padded planes
#define FWD 21
#define FPIX 441   // 21*21 zero-padded food
#define NT 768     // 12 waves, 3/SIMD; waves 0-7 own pixels (37 each), wave 8 does select

typedef float v2f __attribute__((ext_vector_type(2)));

__device__ __forceinline__ v2f vfma2(v2f a, v2f b, v2f c) {
  return __builtin_elementwise_fma(a, b, c);
}

__global__ __launch_bounds__(NT, 3) void ca_kernel(
    const float* __restrict__ cell_in, const float* __restrict__ food_in,
    const int* __restrict__ steps_in,
    const float* __restrict__ fc1_w, const float* __restrict__ fc1_b,
    const float* __restrict__ fc2_w, const float* __restrict__ fc2_b,
    float* __restrict__ out)
{
  __shared__ float s_cell[3][PPIX];          // ch0..2 (ch3==scent, in regs)
  __shared__ float s_x0[PPIX];               // scent stage, then pre-mask x0 plane
  __shared__ __align__(16) float s_v[320];   // masked x0 values; [289..320)=0 pads
  __shared__ float4 s_y4[3][320];            // per-pixel y (12 floats as 3 float4)
  __shared__ float4 s_pd[12][292];           // per-wave partial deltas
  __shared__ float  s_food[FPIX];
  __shared__ int    s_red[8];
  __shared__ float  s_sum[12];
  __shared__ unsigned s_kth;

  const int b    = blockIdx.x;
  const int tid  = threadIdx.x;
  const int lane = tid & 63;
  const int wv   = tid >> 6;
  const int p    = wv * 37 + lane;                         // compact pixel index
  const bool act = (wv < 8) && (lane < 37) && (p < NPIX);
  const int pv   = act ? p : 0;
  const int py   = pv / WD, px = pv - py * WD;
  const int pp   = (py + 1) * PWD + px + 1;
  const int fp   = (py + 2) * FWD + px + 2;

  // ---------------- init ----------------
  for (int i = tid; i < 3 * PPIX; i += NT) (&s_cell[0][0])[i] = 0.f;
  for (int i = tid; i < PPIX; i += NT) s_x0[i] = 0.f;
  for (int i = tid; i < 320; i += NT) s_v[i] = 0.f;
  for (int i = tid; i < FPIX; i += NT) s_food[i] = 0.f;
  __syncthreads();

  float o0 = 0.f, o1 = 0.f, o2 = 0.f, o3 = 0.f;
  if (act) {
    const float* cb = cell_in + (size_t)b * (4 * NPIX);
    o0 = cb[p]; o1 = cb[NPIX + p]; o2 = cb[2 * NPIX + p]; o3 = cb[3 * NPIX + p];
    s_cell[0][pp] = o0; s_cell[1][pp] = o1; s_cell[2][pp] = o2;
    s_food[fp] = food_in[(size_t)b * NPIX + p];
  }
  __syncthreads();

  // weights -> VGPRs/SGPRs, hidden units [h0, h0+6), zero-padded past 64
  const int h0 = __builtin_amdgcn_readfirstlane(wv * 6);
  v2f  w1p[6][6];   // d-pairs: (w[h][2dd], w[h][2dd+1])
  v2f  b1v[6];      // (bias, 0)
  float w2s[6][4];
  #pragma unroll
  for (int j = 0; j < 6; ++j) {
    const int h = h0 + j;
    const bool ok = h < 64;
    #pragma unroll
    for (int dd = 0; dd < 6; ++dd) {
      v2f w; w.x = ok ? fc1_w[h * 12 + 2 * dd] : 0.f;
      w.y = ok ? fc1_w[h * 12 + 2 * dd + 1] : 0.f;
      w1p[j][dd] = w;
    }
    v2f bb; bb.x = ok ? fc1_b[h] : 0.f; bb.y = 0.f;
    b1v[j] = bb;
    #pragma unroll
    for (int c = 0; c < 4; ++c) w2s[j][c] = ok ? fc2_w[c * 64 + h] : 0.f;
  }
  const float b20 = fc2_b[0], b21 = fc2_b[1], b22 = fc2_b[2], b23 = fc2_b[3];

  // scent (constant over steps): conv5x5(food), staged into s_x0 temp
  float scent = 0.f;
  if (act) {
    const float w5[5][5] = {
      {0.f,0.125f,0.25f,0.125f,0.f},
      {0.125f,0.25f,0.5f,0.25f,0.125f},
      {0.25f,0.5f,1.0f,0.5f,0.25f},
      {0.125f,0.25f,0.5f,0.25f,0.125f},
      {0.f,0.125f,0.25f,0.125f,0.f}};
    #pragma unroll
    for (int ky = 0; ky < 5; ++ky)
      #pragma unroll
      for (int kx = 0; kx < 5; ++kx)
        if (w5[ky][kx] != 0.f)
          scent = fmaf(w5[ky][kx], s_food[fp + (ky - 2) * FWD + kx - 2], scent);
    s_x0[pp] = scent;
  }
  __syncthreads();

  // constant Sobel of scent + initial living ballot
  float dxs = 0.f, dys = 0.f;
  if (act) {
    const int q = pp;
    float t00=s_x0[q-PWD-1], t01=s_x0[q-PWD], t02=s_x0[q-PWD+1];
    float t10=s_x0[q-1],                      t12=s_x0[q+1];
    float t20=s_x0[q+PWD-1], t21=s_x0[q+PWD], t22=s_x0[q+PWD+1];
    dxs = ((t02-t00)+2.f*(t12-t10)+(t22-t20))*0.125f;
    dys = ((t20-t00)+2.f*(t21-t01)+(t22-t02))*0.125f;
  }
  if (wv < 8) {
    unsigned long long m = __ballot(act && (o0 > 0.1f));
    if (lane == 0) s_red[wv] = (int)__popcll(m);
  }
  __syncthreads();

  const int steps = steps_in[0];
  float x0 = 0.f, x1 = 0.f, x2 = 0.f, x3 = 0.f;
  bool pre = false;

  for (int s = 0; s < steps; ++s) {
    // ---- A: stencils -> y (act waves) ----
    if (act) {
      const int q = pp;
      float a00=s_cell[0][q-PWD-1], a01=s_cell[0][q-PWD], a02=s_cell[0][q-PWD+1];
      float a10=s_cell[0][q-1],     a12=s_cell[0][q+1];
      float a20=s_cell[0][q+PWD-1], a21=s_cell[0][q+PWD], a22=s_cell[0][q+PWD+1];
      float b00=s_cell[1][q-PWD-1], b01=s_cell[1][q-PWD], b02=s_cell[1][q-PWD+1];
      float b10=s_cell[1][q-1],     b12=s_cell[1][q+1];
      float b20=s_cell[1][q+PWD-1], b21=s_cell[1][q+PWD], b22=s_cell[1][q+PWD+1];
      float c00=s_cell[2][q-PWD-1], c01=s_cell[2][q-PWD], c02=s_cell[2][q-PWD+1];
      float c10=s_cell[2][q-1],     c12=s_cell[2][q+1];
      float c20=s_cell[2][q+PWD-1], c21=s_cell[2][q+PWD], c22=s_cell[2][q+PWD+1];
      float mx = fmaxf(fmaxf(fmaxf(fmaxf(a00,a01),fmaxf(a02,a10)),
                             fmaxf(fmaxf(o0,a12),fmaxf(a20,a21))), a22);
      pre = mx > 0.1f;
      float4 q0, q1, q2;
      q0.x=o0; q0.y=o1; q0.z=o2; q0.w=scent;
      q1.x=((a02-a00)+2.f*(a12-a10)+(a22-a20))*0.125f;
      q1.y=((b02-b00)+2.f*(b12-b10)+(b22-b20))*0.125f;
      q1.z=((c02-c00)+2.f*(c12-c10)+(c22-c20))*0.125f;
      q1.w=dxs;
      q2.x=((a20-a00)+2.f*(a21-a01)+(a22-a02))*0.125f;
      q2.y=((b20-b00)+2.f*(b21-b01)+(b22-b02))*0.125f;
      q2.z=((c20-c00)+2.f*(c21-c01)+(c22-c02))*0.125f;
      q2.w=dys;
      s_y4[0][p]=q0; s_y4[1][p]=q1; s_y4[2][p]=q2;
    }
    __syncthreads();

    // ---- B: hidden-parallel MLP, packed-fp32 d-pairs, weights resident ----
    #pragma unroll 1
    for (int c = 0; c < 5; ++c) {
      const int qx = c * 64 + lane;        // 0..319, in-bounds; garbage rows gated below
      float4 q0 = s_y4[0][qx], q1 = s_y4[1][qx], q2 = s_y4[2][qx];
      v2f y01; y01.x=q0.x; y01.y=q0.y;
      v2f y23; y23.x=q0.z; y23.y=q0.w;
      v2f y45; y45.x=q1.x; y45.y=q1.y;
      v2f y67; y67.x=q1.z; y67.y=q1.w;
      v2f y89; y89.x=q2.x; y89.y=q2.y;
      v2f yab; yab.x=q2.z; yab.y=q2.w;
      float acc0=0.f, acc1=0.f, acc2=0.f, acc3=0.f;
      #pragma unroll
      for (int j = 0; j < 6; ++j) {
        v2f a = b1v[j];
        a = vfma2(w1p[j][0], y01, a);
        a = vfma2(w1p[j][1], y23, a);
        a = vfma2(w1p[j][2], y45, a);
        a = vfma2(w1p[j][3], y67, a);
        a = vfma2(w1p[j][4], y89, a);
        a = vfma2(w1p[j][5], yab, a);
        float g = fmaxf(a.x + a.y, 0.f);
        acc0 = fmaf(w2s[j][0], g, acc0);
        acc1 = fmaf(w2s[j][1], g, acc1);
        acc2 = fmaf(w2s[j][2], g, acc2);
        acc3 = fmaf(w2s[j][3], g, acc3);
      }
      if (qx < NPIX) {
        float4 r; r.x=acc0; r.y=acc1; r.z=acc2; r.w=acc3;
        s_pd[wv][qx] = r;
      }
    }
    __syncthreads();

    // ---- C: combine 12 partials -> x; stage x0 plane ----
    if (act) {
      float dx=0.f, dy=0.f, dz=0.f, dw=0.f;
      #pragma unroll
      for (int w = 0; w < 12; ++w) {
        float4 t = s_pd[w][p];
        dx += t.x; dy += t.y; dz += t.z; dw += t.w;
      }
      x0 = o0 + dx + b20; x1 = o1 + dy + b21;
      x2 = o2 + dz + b22; x3 = scent + dw + b23;
      s_x0[pp] = x0;
    }
    __syncthreads();

    // ---- D: post-mask maxpool, clip, stage selection values ----
    if (act) {
      const int q = pp;
      float m0 = fmaxf(fmaxf(fmaxf(fmaxf(s_x0[q-PWD-1],s_x0[q-PWD]),
                                   fmaxf(s_x0[q-PWD+1],s_x0[q-1])),
                             fmaxf(fmaxf(x0,s_x0[q+1]),
                                   fmaxf(s_x0[q+PWD-1],s_x0[q+PWD]))), s_x0[q+PWD+1]);
      bool km = pre && (m0 > 0.1f);
      o0 = km ? fminf(fmaxf(x0,   0.f),  1.f) : 0.f;  // clip[-10,10] then [0,1] == [0,1]
      o1 = km ? fminf(fmaxf(x1, -10.f), 10.f) : 0.f;
      o2 = km ? fminf(fmaxf(x2, -10.f), 10.f) : 0.f;
      o3 = km ? fminf(fmaxf(x3, -10.f), 10.f) : 0.f;
      s_v[p] = o0; s_cell[1][pp] = o1; s_cell[2][pp] = o2;
    }
    __syncthreads();

    // ---- E: exact k-th-largest via 30-bit radix select (single wave) ----
    if (wv == 8) {
      int r = (lane < 8) ? s_red[lane] : 0;
      r += __shfl_down(r, 4, 64);
      r += __shfl_down(r, 2, 64);
      r += __shfl_down(r, 1, 64);
      int kc = __builtin_amdgcn_readfirstlane(r);
      int k_idx = kc - 1; if (k_idx < 0) k_idx += NPIX;  // torch negative-index wrap
      const unsigned k = (unsigned)(k_idx + 1);
      const uint4 va = ((const uint4*)s_v)[lane];        // vals 4l..4l+3  (0..255)
      const unsigned vb = ((const unsigned*)s_v)[256 + lane];  // vals 256..319 (pads=0)
      unsigned t = 0;
      for (int bit = 29; bit >= 0; --bit) {
        unsigned cand = t | (1u << bit);
        unsigned c = (unsigned)__popcll(__ballot(va.x >= cand))
                   + (unsigned)__popcll(__ballot(va.y >= cand))
                   + (unsigned)__popcll(__ballot(va.z >= cand))
                   + (unsigned)__popcll(__ballot(va.w >= cand))
                   + (unsigned)__popcll(__ballot(vb   >= cand));
        if (c >= k) t = cand;   // largest x with count_ge(x) >= k  == kth value bits
      }
      if (lane == 0) s_kth = t;
    }
    __syncthreads();

    // ---- F: apply keep (v >= kth), write ch0, living ballot ----
    {
      const unsigned kth = s_kth;
      bool alive = false;
      if (act) {
        if (__float_as_uint(o0) < kth) o0 = 0.f;  // nonneg floats: uint cmp == float cmp
        s_cell[0][pp] = o0;
        alive = o0 > 0.1f;
      }
      if (wv < 8) {
        unsigned long long m = __ballot(alive);
        if (lane == 0) s_red[wv] = (int)__popcll(m);
      }
    }
    __syncthreads();
  }

  // ---- outputs: cell | food | total_pixel_val | living_count ----
  if (act) {
    float* oc = out + (size_t)b * (4 * NPIX);
    oc[p] = o0; oc[NPIX + p] = o1; oc[2*NPIX + p] = o2; oc[3*NPIX + p] = o3;
    out[NB*4*NPIX + (size_t)b * NPIX + p] = food_in[(size_t)b * NPIX + p];
  }
  float sv = act ? o0 : 0.f;
  #pragma unroll
  for (int off = 32; off > 0; off >>= 1) sv += __shfl_down(sv, off, 64);
  if (lane == 0) s_sum[wv] = sv;
  __syncthreads();
  if (tid == 0) {
    float tot = 0.f;
    #pragma unroll
    for (int w = 0; w < 12; ++w) tot += s_sum[w];
    int kc = 0;
    #pragma unroll
    for (int w = 0; w < 8; ++w) kc += s_red[w];
    out[NB*4*NPIX + NB*NPIX + b]      = tot;
    out[NB*4*NPIX + NB*NPIX + NB + b] = (float)kc;
  }
}

extern "C" void kernel_launch(void* const* d_in, const int* in_sizes, int n_in,
                              void* d_out, int out_size, void* d_ws, size_t ws_size,
                              hipStream_t stream) {
  (void)in_sizes; (void)n_in; (void)d_ws; (void)ws_size; (void)out_size;
  ca_kernel<<<dim3(NB), dim3(NT), 0, stream>>>(
      (const float*)d_in[0], (const float*)d_in[1], (const int*)d_in[2],
      (const float*)d_in[3], (const float*)d_in[4], (const float*)d_in[5],
      (const float*)d_in[6], (float*)d_out);
}

// Round 4
// 2962.592 us; speedup vs baseline: 1.3637x; 1.0446x over previous
//
#include <hip/hip_runtime.h>

#define NB 16
#define WD 17
#define NPIX 289
#define PWD 19
#define PPIX 361   // 19*19 zero-padded
#define FWD 21
#define FPIX 441   // 21*21 zero-padded food
#define NT 512     // 8 waves, 2/SIMD; every wave: 37 pixels + 8 hidden units

typedef float v2f __attribute__((ext_vector_type(2)));

__device__ __forceinline__ v2f vfma2(v2f a, v2f b, v2f c) {
  return __builtin_elementwise_fma(a, b, c);
}

__global__ __launch_bounds__(NT)
__attribute__((amdgpu_waves_per_eu(2, 2)))
void ca_kernel(
    const float* __restrict__ cell_in, const float* __restrict__ food_in,
    const int* __restrict__ steps_in,
    const float* __restrict__ fc1_w, const float* __restrict__ fc1_b,
    const float* __restrict__ fc2_w, const float* __restrict__ fc2_b,
    float* __restrict__ out)
{
  __shared__ float4 s_cellv[PPIX];               // (ch0,ch1,ch2,scent), zero borders
  __shared__ float  s_x0[PPIX];                  // pre-mask x0 plane (borders 0)
  __shared__ __align__(16) float s_v[320];       // masked x0; [289..320)=0 pads
  __shared__ float4 s_y0[320], s_y1[320], s_y2[320];
  __shared__ float4 s_pd[8][320];                // per-wave partial deltas
  __shared__ float  s_food[FPIX];
  __shared__ float  s_w[1088];                   // fc1_w 768 | fc1_b 64 | fc2_w 256
  __shared__ int    s_red[8];
  __shared__ float  s_sum[8];

  const int b    = blockIdx.x;
  const int tid  = threadIdx.x;
  const int lane = tid & 63;
  const int wv   = tid >> 6;
  const int p    = wv * 37 + lane;               // compact pixel index
  const bool act = (lane < 37) && (p < NPIX);
  const int pv   = act ? p : 0;
  const int py   = pv / WD, px = pv - py * WD;
  const int pp   = (py + 1) * PWD + px + 1;
  const int fp   = (py + 2) * FWD + px + 2;

  // ---------------- init ----------------
  for (int i = tid; i < PPIX; i += NT) { float4 z; z.x=z.y=z.z=z.w=0.f; s_cellv[i]=z; }
  for (int i = tid; i < PPIX; i += NT) s_x0[i] = 0.f;
  for (int i = tid; i < 320;  i += NT) s_v[i] = 0.f;
  for (int i = tid; i < FPIX; i += NT) s_food[i] = 0.f;
  for (int i = tid; i < 768;  i += NT) s_w[i] = fc1_w[i];
  for (int i = tid; i < 64;   i += NT) s_w[768 + i] = fc1_b[i];
  for (int i = tid; i < 256;  i += NT) s_w[832 + i] = fc2_w[i];
  __syncthreads();

  float o0 = 0.f, o1 = 0.f, o2 = 0.f, o3 = 0.f;
  if (act) {
    const float* cb = cell_in + (size_t)b * (4 * NPIX);
    o0 = cb[p]; o1 = cb[NPIX + p]; o2 = cb[2 * NPIX + p]; o3 = cb[3 * NPIX + p];
    s_food[fp] = food_in[(size_t)b * NPIX + p];
  }
  __syncthreads();

  // weights -> VGPRs from LDS (wave wv owns hidden units [8wv, 8wv+8))
  const int h0 = wv * 8;
  v2f w1p[8][6], b1v[8], w2p01[8], w2p23[8];
  #pragma unroll
  for (int j = 0; j < 8; ++j) {
    const int h = h0 + j;
    #pragma unroll
    for (int dd = 0; dd < 6; ++dd) {
      v2f w; w.x = s_w[h * 12 + 2 * dd]; w.y = s_w[h * 12 + 2 * dd + 1];
      w1p[j][dd] = w;
    }
    v2f bb; bb.x = s_w[768 + h]; bb.y = 0.f; b1v[j] = bb;
    v2f wa; wa.x = s_w[832 + 0 * 64 + h]; wa.y = s_w[832 + 1 * 64 + h]; w2p01[j] = wa;
    v2f wb; wb.x = s_w[832 + 2 * 64 + h]; wb.y = s_w[832 + 3 * 64 + h]; w2p23[j] = wb;
  }
  const float b20 = fc2_b[0], b21 = fc2_b[1], b22 = fc2_b[2], b23 = fc2_b[3];

  // scent = conv5x5(food), constant; stage into s_x0 to get its Sobel
  float scent = 0.f;
  if (act) {
    const float w5[5][5] = {
      {0.f,0.125f,0.25f,0.125f,0.f},
      {0.125f,0.25f,0.5f,0.25f,0.125f},
      {0.25f,0.5f,1.0f,0.5f,0.25f},
      {0.125f,0.25f,0.5f,0.25f,0.125f},
      {0.f,0.125f,0.25f,0.125f,0.f}};
    #pragma unroll
    for (int ky = 0; ky < 5; ++ky)
      #pragma unroll
      for (int kx = 0; kx < 5; ++kx)
        if (w5[ky][kx] != 0.f)
          scent = fmaf(w5[ky][kx], s_food[fp + (ky - 2) * FWD + kx - 2], scent);
    s_x0[pp] = scent;
    float4 cv; cv.x = o0; cv.y = o1; cv.z = o2; cv.w = scent;
    s_cellv[pp] = cv;
  }
  __syncthreads();

  float dxs = 0.f, dys = 0.f;
  if (act) {
    const int q = pp;
    float t00=s_x0[q-PWD-1], t01=s_x0[q-PWD], t02=s_x0[q-PWD+1];
    float t10=s_x0[q-1],                      t12=s_x0[q+1];
    float t20=s_x0[q+PWD-1], t21=s_x0[q+PWD], t22=s_x0[q+PWD+1];
    dxs = ((t02-t00)+2.f*(t12-t10)+(t22-t20))*0.125f;
    dys = ((t20-t00)+2.f*(t21-t01)+(t22-t02))*0.125f;
  }
  {
    unsigned long long m = __ballot(act && (o0 > 0.1f));
    if (lane == 0) s_red[wv] = (int)__popcll(m);
  }
  __syncthreads();

  const int steps = steps_in[0];
  float x0 = 0.f, x1 = 0.f, x2 = 0.f, x3 = 0.f;
  bool pre = false;

  for (int s = 0; s < steps; ++s) {
    // ---- A: 8-neighbor float4 stencil -> pre-mask + y; stage y ----
    if (act) {
      const int q = pp;
      float4 n00 = s_cellv[q-PWD-1], n01 = s_cellv[q-PWD], n02 = s_cellv[q-PWD+1];
      float4 n10 = s_cellv[q-1],                           n12 = s_cellv[q+1];
      float4 n20 = s_cellv[q+PWD-1], n21 = s_cellv[q+PWD], n22 = s_cellv[q+PWD+1];
      float mx = fmaxf(fmaxf(fmaxf(fmaxf(n00.x,n01.x),fmaxf(n02.x,n10.x)),
                             fmaxf(fmaxf(o0,n12.x),fmaxf(n20.x,n21.x))), n22.x);
      pre = mx > 0.1f;
      float4 q0; q0.x=o0; q0.y=o1; q0.z=o2; q0.w=scent;
      float4 dx4, dy4;
      dx4.x = ((n02.x-n00.x)+2.f*(n12.x-n10.x)+(n22.x-n20.x))*0.125f;
      dx4.y = ((n02.y-n00.y)+2.f*(n12.y-n10.y)+(n22.y-n20.y))*0.125f;
      dx4.z = ((n02.z-n00.z)+2.f*(n12.z-n10.z)+(n22.z-n20.z))*0.125f;
      dx4.w = dxs;
      dy4.x = ((n20.x-n00.x)+2.f*(n21.x-n01.x)+(n22.x-n02.x))*0.125f;
      dy4.y = ((n20.y-n00.y)+2.f*(n21.y-n01.y)+(n22.y-n02.y))*0.125f;
      dy4.z = ((n20.z-n00.z)+2.f*(n21.z-n01.z)+(n22.z-n02.z))*0.125f;
      dy4.w = dys;
      s_y0[p] = q0; s_y1[p] = dx4; s_y2[p] = dy4;
    }
    __syncthreads();

    // ---- B: hidden-parallel MLP, weights in VGPRs, packed fp32 ----
    #pragma unroll 1
    for (int c = 0; c < 5; ++c) {
      const int qx = c * 64 + lane;   // 0..319 in-bounds; garbage gated below
      float4 q0 = s_y0[qx], q1 = s_y1[qx], q2 = s_y2[qx];
      v2f y01; y01.x=q0.x; y01.y=q0.y;
      v2f y23; y23.x=q0.z; y23.y=q0.w;
      v2f y45; y45.x=q1.x; y45.y=q1.y;
      v2f y67; y67.x=q1.z; y67.y=q1.w;
      v2f y89; y89.x=q2.x; y89.y=q2.y;
      v2f yab; yab.x=q2.z; yab.y=q2.w;
      v2f acc01; acc01.x = 0.f; acc01.y = 0.f;
      v2f acc23; acc23.x = 0.f; acc23.y = 0.f;
      #pragma unroll
      for (int j = 0; j < 8; ++j) {
        v2f a = b1v[j];
        a = vfma2(w1p[j][0], y01, a);
        a = vfma2(w1p[j][1], y23, a);
        a = vfma2(w1p[j][2], y45, a);
        a = vfma2(w1p[j][3], y67, a);
        a = vfma2(w1p[j][4], y89, a);
        a = vfma2(w1p[j][5], yab, a);
        float g = fmaxf(a.x + a.y, 0.f);
        v2f gg; gg.x = g; gg.y = g;
        acc01 = vfma2(w2p01[j], gg, acc01);
        acc23 = vfma2(w2p23[j], gg, acc23);
      }
      if (qx < NPIX) {
        float4 r; r.x=acc01.x; r.y=acc01.y; r.z=acc23.x; r.w=acc23.y;
        s_pd[wv][qx] = r;
      }
    }
    __syncthreads();

    // ---- C: sum 8 partials -> x; stage x0 plane ----
    if (act) {
      float4 d = s_pd[0][p];
      #pragma unroll
      for (int w = 1; w < 8; ++w) {
        float4 t = s_pd[w][p];
        d.x += t.x; d.y += t.y; d.z += t.z; d.w += t.w;
      }
      x0 = o0 + d.x + b20; x1 = o1 + d.y + b21;
      x2 = o2 + d.z + b22; x3 = scent + d.w + b23;
      s_x0[pp] = x0;
    }
    __syncthreads();

    // ---- D: post-mask maxpool, clip, stage s_v + cell float4 ----
    if (act) {
      const int q = pp;
      float m0 = fmaxf(fmaxf(fmaxf(fmaxf(s_x0[q-PWD-1],s_x0[q-PWD]),
                                   fmaxf(s_x0[q-PWD+1],s_x0[q-1])),
                             fmaxf(fmaxf(x0,s_x0[q+1]),
                                   fmaxf(s_x0[q+PWD-1],s_x0[q+PWD]))), s_x0[q+PWD+1]);
      bool km = pre && (m0 > 0.1f);
      o0 = km ? fminf(fmaxf(x0,   0.f),  1.f) : 0.f;  // clip[-10,10] then [0,1] == [0,1]
      o1 = km ? fminf(fmaxf(x1, -10.f), 10.f) : 0.f;
      o2 = km ? fminf(fmaxf(x2, -10.f), 10.f) : 0.f;
      o3 = km ? fminf(fmaxf(x3, -10.f), 10.f) : 0.f;
      s_v[p] = o0;
      float4 cv; cv.x = o0; cv.y = o1; cv.z = o2; cv.w = scent;
      s_cellv[pp] = cv;
    }
    __syncthreads();

    // ---- E (every wave, redundant): k-cnt + 30-bit radix select ----
    unsigned kth;
    {
      int r = (lane < 8) ? s_red[lane] : 0;
      r += __shfl_down(r, 4, 64);
      r += __shfl_down(r, 2, 64);
      r += __shfl_down(r, 1, 64);
      int kc = __builtin_amdgcn_readfirstlane(r);
      int k_idx = kc - 1; if (k_idx < 0) k_idx += NPIX;  // torch wrap
      if (k_idx >= NPIX - 1) {
        kth = 0u;                       // keep-all
      } else {
        const unsigned k = (unsigned)(k_idx + 1);
        const uint4 va = ((const uint4*)s_v)[lane];            // 0..255
        const unsigned vb = ((const unsigned*)s_v)[256 + lane];// 256..319 (pads 0)
        unsigned t = 0;
        #pragma unroll 1
        for (int bit = 29; bit >= 0; --bit) {
          unsigned cand = t | (1u << bit);
          unsigned c = (unsigned)__popcll(__ballot(va.x >= cand))
                     + (unsigned)__popcll(__ballot(va.y >= cand))
                     + (unsigned)__popcll(__ballot(va.z >= cand))
                     + (unsigned)__popcll(__ballot(va.w >= cand))
                     + (unsigned)__popcll(__ballot(vb   >= cand));
          if (c >= k) t = cand;   // largest x with count_ge(x) >= k == kth bits
        }
        kth = t;
      }
    }
    // ---- F: apply keep, write ch0, living ballot ----
    {
      bool alive = false;
      if (act) {
        if (__float_as_uint(o0) < kth) o0 = 0.f;  // nonneg: uint cmp == float cmp
        ((float*)s_cellv)[pp * 4] = o0;
        alive = o0 > 0.1f;
      }
      unsigned long long m = __ballot(alive);
      if (lane == 0) s_red[wv] = (int)__popcll(m);
    }
    __syncthreads();
  }

  // ---- outputs: cell | food | total_pixel_val | living_count ----
  if (act) {
    float* oc = out + (size_t)b * (4 * NPIX);
    oc[p] = o0; oc[NPIX + p] = o1; oc[2*NPIX + p] = o2; oc[3*NPIX + p] = o3;
    out[NB*4*NPIX + (size_t)b * NPIX + p] = food_in[(size_t)b * NPIX + p];
  }
  float sv = act ? o0 : 0.f;
  #pragma unroll
  for (int off = 32; off > 0; off >>= 1) sv += __shfl_down(sv, off, 64);
  if (lane == 0) s_sum[wv] = sv;
  __syncthreads();
  if (tid == 0) {
    float tot = 0.f; int kc = 0;
    #pragma unroll
    for (int w = 0; w < 8; ++w) { tot += s_sum[w]; kc += s_red[w]; }
    out[NB*4*NPIX + NB*NPIX + b]      = tot;
    out[NB*4*NPIX + NB*NPIX + NB + b] = (float)kc;
  }
}

extern "C" void kernel_launch(void* const* d_in, const int* in_sizes, int n_in,
                              void* d_out, int out_size, void* d_ws, size_t ws_size,
                              hipStream_t stream) {
  (void)in_sizes; (void)n_in; (void)d_ws; (void)ws_size; (void)out_size;
  ca_kernel<<<dim3(NB), dim3(NT), 0, stream>>>(
      (const float*)d_in[0], (const float*)d_in[1], (const int*)d_in[2],
      (const float*)d_in[3], (const float*)d_in[4], (const float*)d_in[5],
      (const float*)d_in[6], (float*)d_out);
}